// Round 10
// baseline (403.179 us; speedup 1.0000x reference)
//
#include <hip/hip_runtime.h>
#include <stdint.h>

#define GD 128
#define H1 128
#define H2 128
#define NBASES 32
#define NREL 8
#define K1 (NREL*GD + GD)   // 1152
#define AROW 580            // LDS A-tile row stride in uint32 (2-way bank aliasing = free)

typedef __attribute__((ext_vector_type(8))) short bf16x8;
typedef __attribute__((ext_vector_type(4))) float f32x4;

static inline size_t align256(size_t x){ return (x + 255) & ~(size_t)255; }

__device__ __forceinline__ float bf2f(uint32_t u16){
  union { uint32_t u; float f; } c; c.u = (u16 & 0xffffu) << 16; return c.f;
}
__device__ __forceinline__ unsigned short f2bf(float f){
  union { float f; uint32_t u; } c; c.f = f;
  uint32_t u = c.u;
  u += 0x7fffu + ((u >> 16) & 1u);   // RTNE (finite inputs)
  return (unsigned short)(u >> 16);
}
__device__ __forceinline__ uint32_t pkbf(float a, float b){
  union { float f; uint32_t u; } ca, cb; ca.f = a; cb.f = b;
  return __builtin_amdgcn_perm(cb.u + 0x8000u, ca.u + 0x8000u, 0x07060302u);
}

// ==== merged prep: B1t build | B2t build | x cast | r-major hist ====
__global__ void k_prep(const float* __restrict__ comp, const float* __restrict__ basis,
                       const float* __restrict__ root, unsigned short* __restrict__ B1t,
                       const float* __restrict__ wk, const float* __restrict__ wq,
                       const float* __restrict__ wv, const float* __restrict__ wsk,
                       const float* __restrict__ bk, const float* __restrict__ bq,
                       const float* __restrict__ bv, const float* __restrict__ bs,
                       unsigned short* __restrict__ B2t, float* __restrict__ Bb,
                       const float4* __restrict__ x, uint2* __restrict__ xout, int cnt4,
                       const int* __restrict__ edst, const int* __restrict__ etyp,
                       int* __restrict__ cnt, int E, int n){
  int b = blockIdx.x, t = threadIdx.x;
  if (b < 576){
    // B1t[o][k]: k<1024 -> W_r[i=k&127][o], else root[k-1024][o]
    int idx = b*256 + t;                 // < 147456 = 128*1152
    int nn = idx / K1, kk = idx % K1;
    float v;
    if (kk < NREL*GD){
      int r = kk >> 7, i = kk & 127;
      float acc = 0.f;
      #pragma unroll
      for (int bb = 0; bb < NBASES; ++bb)
        acc += comp[r*NBASES + bb] * basis[((size_t)bb*GD + i)*H1 + nn];
      v = acc;
    } else {
      v = root[(size_t)(kk - NREL*GD)*H1 + nn];
    }
    B1t[idx] = f2bf(v);
  } else if (b < 576 + 256){
    int idx = (b - 576)*256 + t;         // < 65536 = 512*H1
    int c = idx / H1, k = idx % H1;
    const float* w = (c < 128) ? wk : (c < 256) ? wq : (c < 384) ? wv : wsk;
    B2t[idx] = f2bf(w[(size_t)k*H2 + (c & 127)]);
    if (idx < 512){
      const float* bia = (idx < 128) ? bk : (idx < 256) ? bq : (idx < 384) ? bv : bs;
      Bb[idx] = bia[idx & 127];
    }
  } else {
    int cb = b - (576 + 256);
    int ncastb = (cnt4 + 255) >> 8;
    if (cb < ncastb){
      int i = cb*256 + t;
      if (i < cnt4){
        float4 v = x[i];
        uint2 o; o.x = pkbf(v.x, v.y); o.y = pkbf(v.z, v.w);
        xout[i] = o;
      }
    } else {
      int e = (cb - ncastb)*256 + t;
      if (e < E) atomicAdd(&cnt[etyp[e]*n + edst[e]], 1);
    }
  }
}

// ---- parallel scan, stage A ----
__global__ void k_scanA(const int* __restrict__ deg, int* __restrict__ off,
                        int* __restrict__ btot, int len){
  __shared__ int wsum[16];
  int t = threadIdx.x, lane = t & 63, w = t >> 6;
  int i0 = blockIdx.x*8192 + t*8;
  int v[8];
  if (i0 + 7 < len){
    int4 va = *(const int4*)(deg + i0);
    int4 vb = *(const int4*)(deg + i0 + 4);
    v[0]=va.x; v[1]=va.y; v[2]=va.z; v[3]=va.w;
    v[4]=vb.x; v[5]=vb.y; v[6]=vb.z; v[7]=vb.w;
  } else {
    #pragma unroll
    for (int u = 0; u < 8; ++u) v[u] = (i0+u < len) ? deg[i0+u] : 0;
  }
  int s[8]; s[0] = v[0];
  #pragma unroll
  for (int u = 1; u < 8; ++u) s[u] = s[u-1] + v[u];
  int x = s[7];
  #pragma unroll
  for (int d = 1; d < 64; d <<= 1){
    int u = __shfl_up(x, d, 64);
    if (lane >= d) x += u;
  }
  if (lane == 63) wsum[w] = x;
  __syncthreads();
  if (t < 16){
    int y = wsum[t];
    #pragma unroll
    for (int d = 1; d < 16; d <<= 1){
      int u = __shfl_up(y, d, 16);
      if (t >= d) y += u;
    }
    wsum[t] = y;
  }
  __syncthreads();
  int woff = (w > 0) ? wsum[w-1] : 0;
  int excl = woff + x - s[7];
  #pragma unroll
  for (int u = 0; u < 8; ++u)
    if (i0+u < len) off[i0+u] = excl + s[u] - v[u];
  if (t == 0) btot[blockIdx.x] = wsum[15];
}

// ---- scan stage B ----
__global__ void k_scanB(const int* __restrict__ btot, int* __restrict__ off,
                        int* __restrict__ cursor, int len, int sentinel){
  int t = threadIdx.x, bid = blockIdx.x;
  int add = 0;
  for (int j = 0; j < bid; ++j) add += btot[j];
  int i0 = bid*8192 + t*8;
  #pragma unroll
  for (int u = 0; u < 8; ++u){
    int i = i0 + u;
    if (i < len){ int val = off[i] + add; off[i] = val; cursor[i] = val; }
  }
  if (bid == 0 && t == 0) off[len] = sentinel;
}

// pk[pos] = src, (r,dst)-sorted
__global__ void k_scatter_rd(const int* __restrict__ src, const int* __restrict__ dst,
                             const int* __restrict__ typ, int* __restrict__ cursor,
                             int* __restrict__ pk, int E, int n){
  int e = blockIdx.x*blockDim.x + threadIdx.x;
  if (e >= E) return;
  int pos = atomicAdd(&cursor[typ[e]*n + dst[e]], 1);
  pk[pos] = src[e];
}

// ==== fused RGCN: 32 nodes/block (8 waves x 4 nodes). Per-node register-accumulated
// gather (R8-proven loop) -> LDS A-tile (plain ds_write) -> MFMA vs L2-resident B1t. ====
__launch_bounds__(512)
__global__ void k_fused1(const int* __restrict__ off_rd, const int* __restrict__ pk_rd,
                         const unsigned short* __restrict__ xbf,
                         const unsigned short* __restrict__ B1t,
                         const float* __restrict__ bias1,
                         unsigned short* __restrict__ h, int n){
  __shared__ uint32_t Atile[32*AROW];   // 74240 B
  const uint32_t* x32 = (const uint32_t*)xbf;
  int t = threadIdx.x, lane = t & 63, wave = t >> 6;
  int node_base = blockIdx.x * 32;

  // ---- gather phase: this wave fills local rows [wave*4, wave*4+4) ----
  for (int i = 0; i < 4; ++i){
    int m = wave*4 + i;
    int nd = node_base + m;
    uint32_t* Arow = Atile + m*AROW;
    if (nd >= n){
      #pragma unroll
      for (int r = 0; r < 9; ++r) Arow[r*64 + lane] = 0u;
      continue;
    }
    int r8 = lane & 7;
    int o_r = off_rd[(size_t)r8*n + nd];
    int e_r = off_rd[(size_t)r8*n + nd + 1];
    int c_r = e_r - o_r;
    int c0_ = __builtin_amdgcn_readlane(c_r, 0), c1_ = __builtin_amdgcn_readlane(c_r, 1);
    int c2_ = __builtin_amdgcn_readlane(c_r, 2), c3_ = __builtin_amdgcn_readlane(c_r, 3);
    int c4_ = __builtin_amdgcn_readlane(c_r, 4), c5_ = __builtin_amdgcn_readlane(c_r, 5);
    int c6_ = __builtin_amdgcn_readlane(c_r, 6), c7_ = __builtin_amdgcn_readlane(c_r, 7);
    int o0_ = __builtin_amdgcn_readlane(o_r, 0), o1_ = __builtin_amdgcn_readlane(o_r, 1);
    int o2_ = __builtin_amdgcn_readlane(o_r, 2), o3_ = __builtin_amdgcn_readlane(o_r, 3);
    int o4_ = __builtin_amdgcn_readlane(o_r, 4), o5_ = __builtin_amdgcn_readlane(o_r, 5);
    int o6_ = __builtin_amdgcn_readlane(o_r, 6), o7_ = __builtin_amdgcn_readlane(o_r, 7);
    int p1 = c0_, p2 = p1 + c1_, p3 = p2 + c2_, p4 = p3 + c3_;
    int p5 = p4 + c4_, p6 = p5 + c5_, p7 = p6 + c6_, dg = p7 + c7_;

    float a0[8], a1[8];
    #pragma unroll
    for (int r = 0; r < 8; ++r){ a0[r] = 0.f; a1[r] = 0.f; }

    for (int jb = 0; jb < dg; jb += 64){
      int ii = jb + lane;
      int adj = o0_, rel = 0;
      adj = (ii >= p1) ? (o1_ - p1) : adj;  rel += (ii >= p1);
      adj = (ii >= p2) ? (o2_ - p2) : adj;  rel += (ii >= p2);
      adj = (ii >= p3) ? (o3_ - p3) : adj;  rel += (ii >= p3);
      adj = (ii >= p4) ? (o4_ - p4) : adj;  rel += (ii >= p4);
      adj = (ii >= p5) ? (o5_ - p5) : adj;  rel += (ii >= p5);
      adj = (ii >= p6) ? (o6_ - p6) : adj;  rel += (ii >= p6);
      adj = (ii >= p7) ? (o7_ - p7) : adj;  rel += (ii >= p7);
      int mm = dg - jb; if (mm > 64) mm = 64;
      int pj = (lane < mm) ? pk_rd[adj + ii] : 0;
      int jj = 0;
      for (; jj + 8 <= mm; jj += 8){
        uint32_t g[8]; int rr[8];
        #pragma unroll
        for (int k = 0; k < 8; ++k){
          int s = __builtin_amdgcn_readlane(pj, jj + k);
          rr[k] = __builtin_amdgcn_readlane(rel, jj + k);
          g[k] = x32[(size_t)s*64 + lane];
        }
        #pragma unroll
        for (int k = 0; k < 8; ++k){
          float x0 = bf2f(g[k]), x1 = bf2f(g[k] >> 16);
          switch (rr[k]){
            case 0: a0[0]+=x0; a1[0]+=x1; break;
            case 1: a0[1]+=x0; a1[1]+=x1; break;
            case 2: a0[2]+=x0; a1[2]+=x1; break;
            case 3: a0[3]+=x0; a1[3]+=x1; break;
            case 4: a0[4]+=x0; a1[4]+=x1; break;
            case 5: a0[5]+=x0; a1[5]+=x1; break;
            case 6: a0[6]+=x0; a1[6]+=x1; break;
            default: a0[7]+=x0; a1[7]+=x1; break;
          }
        }
      }
      for (; jj + 4 <= mm; jj += 4){
        uint32_t g[4]; int rr[4];
        #pragma unroll
        for (int k = 0; k < 4; ++k){
          int s = __builtin_amdgcn_readlane(pj, jj + k);
          rr[k] = __builtin_amdgcn_readlane(rel, jj + k);
          g[k] = x32[(size_t)s*64 + lane];
        }
        #pragma unroll
        for (int k = 0; k < 4; ++k){
          float x0 = bf2f(g[k]), x1 = bf2f(g[k] >> 16);
          switch (rr[k]){
            case 0: a0[0]+=x0; a1[0]+=x1; break;
            case 1: a0[1]+=x0; a1[1]+=x1; break;
            case 2: a0[2]+=x0; a1[2]+=x1; break;
            case 3: a0[3]+=x0; a1[3]+=x1; break;
            case 4: a0[4]+=x0; a1[4]+=x1; break;
            case 5: a0[5]+=x0; a1[5]+=x1; break;
            case 6: a0[6]+=x0; a1[6]+=x1; break;
            default: a0[7]+=x0; a1[7]+=x1; break;
          }
        }
      }
      for (; jj < mm; ++jj){
        int s = __builtin_amdgcn_readlane(pj, jj);
        int rk = __builtin_amdgcn_readlane(rel, jj);
        uint32_t gg = x32[(size_t)s*64 + lane];
        float x0 = bf2f(gg), x1 = bf2f(gg >> 16);
        switch (rk){
          case 0: a0[0]+=x0; a1[0]+=x1; break;
          case 1: a0[1]+=x0; a1[1]+=x1; break;
          case 2: a0[2]+=x0; a1[2]+=x1; break;
          case 3: a0[3]+=x0; a1[3]+=x1; break;
          case 4: a0[4]+=x0; a1[4]+=x1; break;
          case 5: a0[5]+=x0; a1[5]+=x1; break;
          case 6: a0[6]+=x0; a1[6]+=x1; break;
          default: a0[7]+=x0; a1[7]+=x1; break;
        }
      }
    }
    int cc[8] = {c0_, c1_, c2_, c3_, c4_, c5_, c6_, c7_};
    #pragma unroll
    for (int r = 0; r < 8; ++r){
      float inv = (cc[r] > 0) ? 1.f/(float)cc[r] : 0.f;
      Arow[r*64 + lane] = pkbf(a0[r]*inv, a1[r]*inv);
    }
    Arow[512 + lane] = x32[(size_t)nd*64 + lane];
  }
  __syncthreads();

  // ---- MFMA phase: wave computes output cols [wave*16, wave*16+16) for 32 rows ----
  int mrow = lane & 15, quad = lane >> 4;
  int nr = wave*16 + mrow;                 // output column = B1t row
  const unsigned short* Bp = B1t + (size_t)nr*K1 + quad*8;
  f32x4 acc0 = (f32x4){0.f,0.f,0.f,0.f};
  f32x4 acc1 = (f32x4){0.f,0.f,0.f,0.f};
  #pragma unroll
  for (int c = 0; c < 36; ++c){
    bf16x8 bfr = *(const bf16x8*)(Bp + c*32);
    bf16x8 af0 = *(const bf16x8*)(Atile + mrow*AROW + c*16 + quad*4);
    bf16x8 af1 = *(const bf16x8*)(Atile + (16 + mrow)*AROW + c*16 + quad*4);
    acc0 = __builtin_amdgcn_mfma_f32_16x16x32_bf16(af0, bfr, acc0, 0, 0, 0);
    acc1 = __builtin_amdgcn_mfma_f32_16x16x32_bf16(af1, bfr, acc1, 0, 0, 0);
  }
  float bcol = bias1[nr];
  #pragma unroll
  for (int rg = 0; rg < 4; ++rg){
    int row0 = node_base + quad*4 + rg;
    int row1 = node_base + 16 + quad*4 + rg;
    h[(size_t)row0*H1 + nr] = f2bf(acc0[rg] + bcol);
    h[(size_t)row1*H1 + nr] = f2bf(acc1[rg] + bcol);
  }
}

__device__ __forceinline__ void async_copy16(void* lds_dst, const void* gsrc){
  __builtin_amdgcn_global_load_lds(
      (const __attribute__((address_space(1))) uint32_t*)gsrc,
      (__attribute__((address_space(3))) uint32_t*)lds_dst, 16, 0, 0);
}

// ---- GEMM2 (m97-style): [npad,512] = h @ B2t^T + Bb; skip -> skipb(bf16) ----
__launch_bounds__(256)
__global__ void k_gemm2(const unsigned short* __restrict__ A, const unsigned short* __restrict__ Bt,
                        const float* __restrict__ Bb, unsigned short* __restrict__ kqv,
                        unsigned short* __restrict__ skipb, int n){
  __shared__ char lds[16384];
  int t = threadIdx.x, lane = t & 63, wave = t >> 6;
  int row0 = blockIdx.x * 128;
  int c0 = blockIdx.y * 128;
  int mrow = lane & 15, quad = lane >> 4;
  int wrow = (wave & 1) * 64, wcol = (wave >> 1) * 64;
  int s = (mrow >> 1) & 3;

  const unsigned short* Asrc = A + (size_t)(row0 + (t >> 2))*H1 + (((t & 3) ^ ((t >> 3) & 3)) << 3);
  const unsigned short* Bsrc = Bt + (size_t)(c0 + (t >> 2))*H1 + (((t & 3) ^ ((t >> 3) & 3)) << 3);
  char* ldsw = lds + wave*1024;

  int aoff = (wrow + mrow)*64 + ((quad ^ s) << 4);
  int boff = 8192 + (wcol + mrow)*64 + ((quad ^ s) << 4);

  f32x4 acc[4][4];
  #pragma unroll
  for (int i = 0; i < 4; ++i)
    #pragma unroll
    for (int j = 0; j < 4; ++j) acc[i][j] = (f32x4){0.f,0.f,0.f,0.f};

  #pragma unroll
  for (int kt = 0; kt < H1; kt += 32){
    __syncthreads();
    async_copy16(ldsw,         Asrc + kt);
    async_copy16(ldsw + 4096,  Asrc + (size_t)64*H1 + kt);
    async_copy16(ldsw + 8192,  Bsrc + kt);
    async_copy16(ldsw + 12288, Bsrc + (size_t)64*H1 + kt);
    __syncthreads();
    bf16x8 af[4], bf[4];
    #pragma unroll
    for (int i = 0; i < 4; ++i) af[i] = *(const bf16x8*)(lds + aoff + i*1024);
    #pragma unroll
    for (int j = 0; j < 4; ++j) bf[j] = *(const bf16x8*)(lds + boff + j*1024);
    #pragma unroll
    for (int i = 0; i < 4; ++i)
      #pragma unroll
      for (int j = 0; j < 4; ++j)
        acc[i][j] = __builtin_amdgcn_mfma_f32_16x16x32_bf16(af[i], bf[j], acc[i][j], 0, 0, 0);
  }
  #pragma unroll
  for (int j = 0; j < 4; ++j){
    int col = c0 + wcol + j*16 + mrow;
    float bcol = Bb[col];
    #pragma unroll
    for (int i = 0; i < 4; ++i)
      #pragma unroll
      for (int rg = 0; rg < 4; ++rg){
        int rr = row0 + wrow + i*16 + quad*4 + rg;
        if (rr >= n) continue;
        float v = acc[i][j][rg] + bcol;
        if (col < 128){
          kqv[(size_t)rr*384 + col] = f2bf(v);
        } else if (col < 256){
          int jj = col - 128;
          kqv[(size_t)rr*384 + 128 + ((jj >> 1) << 2) + (jj & 1)] = f2bf(v);
        } else if (col < 384){
          int jj = col - 256;
          kqv[(size_t)rr*384 + 128 + ((jj >> 1) << 2) + 2 + (jj & 1)] = f2bf(v);
        } else {
          skipb[(size_t)rr*H2 + (col - 384)] = f2bf(v);
        }
      }
  }
}

// ---- one wave per dst node: out = sum_e sigmoid(k+q)*v + skip (pure write) ----
__global__ void k_edge2(const int* __restrict__ off_rd, const int* __restrict__ pk_rd,
                        const unsigned short* __restrict__ kqv,
                        const unsigned short* __restrict__ skipb,
                        float* __restrict__ out, int n){
  int wid = blockIdx.x*(blockDim.x >> 6) + (threadIdx.x >> 6);
  int lane = threadIdx.x & 63;
  if (wid >= n) return;
  const uint32_t* kv32 = (const uint32_t*)kqv;
  int r = lane & 7;
  int o_r = off_rd[(size_t)r*n + wid];
  int e_r = off_rd[(size_t)r*n + wid + 1];
  int c_r = e_r - o_r;
  int c0_ = __builtin_amdgcn_readlane(c_r, 0), c1_ = __builtin_amdgcn_readlane(c_r, 1);
  int c2_ = __builtin_amdgcn_readlane(c_r, 2), c3_ = __builtin_amdgcn_readlane(c_r, 3);
  int c4_ = __builtin_amdgcn_readlane(c_r, 4), c5_ = __builtin_amdgcn_readlane(c_r, 5);
  int c6_ = __builtin_amdgcn_readlane(c_r, 6), c7_ = __builtin_amdgcn_readlane(c_r, 7);
  int o0_ = __builtin_amdgcn_readlane(o_r, 0), o1_ = __builtin_amdgcn_readlane(o_r, 1);
  int o2_ = __builtin_amdgcn_readlane(o_r, 2), o3_ = __builtin_amdgcn_readlane(o_r, 3);
  int o4_ = __builtin_amdgcn_readlane(o_r, 4), o5_ = __builtin_amdgcn_readlane(o_r, 5);
  int o6_ = __builtin_amdgcn_readlane(o_r, 6), o7_ = __builtin_amdgcn_readlane(o_r, 7);
  int p1 = c0_, p2 = p1 + c1_, p3 = p2 + c2_, p4 = p3 + c3_;
  int p5 = p4 + c4_, p6 = p5 + c5_, p7 = p6 + c6_, dg = p7 + c7_;

  uint32_t ku = kv32[(size_t)wid*192 + lane];
  float k0 = bf2f(ku), k1 = bf2f(ku >> 16);
  float a0 = 0.f, a1 = 0.f;
  for (int jb = 0; jb < dg; jb += 64){
    int i = jb + lane;
    int adj = o0_;
    adj = (i >= p1) ? (o1_ - p1) : adj;
    adj = (i >= p2) ? (o2_ - p2) : adj;
    adj = (i >= p3) ? (o3_ - p3) : adj;
    adj = (i >= p4) ? (o4_ - p4) : adj;
    adj = (i >= p5) ? (o5_ - p5) : adj;
    adj = (i >= p6) ? (o6_ - p6) : adj;
    adj = (i >= p7) ? (o7_ - p7) : adj;
    int m = dg - jb; if (m > 64) m = 64;
    int pj = (lane < m) ? pk_rd[adj + i] : 0;
    int jj = 0;
    for (; jj + 8 <= m; jj += 8){
      uint2 q[8];
      #pragma unroll
      for (int k = 0; k < 8; ++k){
        int s = __builtin_amdgcn_readlane(pj, jj + k);
        q[k] = *(const uint2*)(kv32 + (size_t)s*192 + 64 + lane*2);
      }
      #pragma unroll
      for (int k = 0; k < 8; ++k){
        float qq0 = bf2f(q[k].x), qq1 = bf2f(q[k].x >> 16);
        float vv0 = bf2f(q[k].y), vv1 = bf2f(q[k].y >> 16);
        float g0 = 1.f / (1.f + __expf(-(k0 + qq0)));
        float g1 = 1.f / (1.f + __expf(-(k1 + qq1)));
        a0 += g0*vv0; a1 += g1*vv1;
      }
    }
    for (; jj + 4 <= m; jj += 4){
      uint2 q[4];
      #pragma unroll
      for (int k = 0; k < 4; ++k){
        int s = __builtin_amdgcn_readlane(pj, jj + k);
        q[k] = *(const uint2*)(kv32 + (size_t)s*192 + 64 + lane*2);
      }
      #pragma unroll
      for (int k = 0; k < 4; ++k){
        float qq0 = bf2f(q[k].x), qq1 = bf2f(q[k].x >> 16);
        float vv0 = bf2f(q[k].y), vv1 = bf2f(q[k].y >> 16);
        float g0 = 1.f / (1.f + __expf(-(k0 + qq0)));
        float g1 = 1.f / (1.f + __expf(-(k1 + qq1)));
        a0 += g0*vv0; a1 += g1*vv1;
      }
    }
    for (; jj < m; ++jj){
      int s = __builtin_amdgcn_readlane(pj, jj);
      uint2 qc = *(const uint2*)(kv32 + (size_t)s*192 + 64 + lane*2);
      float qq0 = bf2f(qc.x), qq1 = bf2f(qc.x >> 16);
      float vv0 = bf2f(qc.y), vv1 = bf2f(qc.y >> 16);
      float g0 = 1.f / (1.f + __expf(-(k0 + qq0)));
      float g1 = 1.f / (1.f + __expf(-(k1 + qq1)));
      a0 += g0*vv0; a1 += g1*vv1;
    }
  }
  uint32_t sk = ((const uint32_t*)skipb)[(size_t)wid*64 + lane];
  float2 cur; cur.x = a0 + bf2f(sk); cur.y = a1 + bf2f(sk >> 16);
  ((float2*)(out + (size_t)wid*H2))[lane] = cur;
}

extern "C" void kernel_launch(void* const* d_in, const int* in_sizes, int n_in,
                              void* d_out, int out_size, void* d_ws, size_t ws_size,
                              hipStream_t stream){
  const float* x     = (const float*)d_in[0];
  const int*   eidx  = (const int*)  d_in[1];
  const int*   etype = (const int*)  d_in[3];
  const float* basis = (const float*)d_in[4];
  const float* comp  = (const float*)d_in[5];
  const float* root  = (const float*)d_in[6];
  const float* bias1 = (const float*)d_in[7];
  const float* wk    = (const float*)d_in[8];
  const float* bk    = (const float*)d_in[9];
  const float* wq    = (const float*)d_in[10];
  const float* bq    = (const float*)d_in[11];
  const float* wv    = (const float*)d_in[12];
  const float* bv    = (const float*)d_in[13];
  const float* wsk   = (const float*)d_in[14];
  const float* bs    = (const float*)d_in[15];
  const int n = in_sizes[0] / GD;          // 50000
  const int E = in_sizes[3];               // 600000
  const int npad = (n + 127) & ~127;       // 50048 (multiple of 32 and 128)
  const int* esrc = eidx;
  const int* edst = eidx + E;
  float* out = (float*)d_out;

  char* w = (char*)d_ws;
  size_t off = 0;
  unsigned short* xbf  = (unsigned short*)(w + off); off = align256(off + (size_t)n*GD*2);
  unsigned short* B1t  = (unsigned short*)(w + off); off = align256(off + (size_t)H1*K1*2);
  unsigned short* B2t  = (unsigned short*)(w + off); off = align256(off + (size_t)512*H1*2);
  float* Bb            = (float*)(w + off);          off = align256(off + 512*4);
  unsigned short* hbuf = (unsigned short*)(w + off); off = align256(off + (size_t)npad*H1*2);
  unsigned short* kqv  = (unsigned short*)(w + off); off = align256(off + (size_t)n*384*2);
  unsigned short* skipb= (unsigned short*)(w + off); off = align256(off + (size_t)npad*H2*2);
  int* cnt_rd          = (int*)(w + off);            off = align256(off + (size_t)(8*n+4)*4);
  int* off_rd          = (int*)(w + off);            off = align256(off + (size_t)(8*n+1)*4);
  int* cur_rd          = (int*)(w + off);            off = align256(off + (size_t)8*n*4);
  int* btot_rd         = (int*)(w + off);            off = align256(off + 64*4);
  int* pk_rd           = (int*)(w + off);            off = align256(off + (size_t)E*4);

  const int nblk_rd = (8*n + 8191) / 8192;       // 49
  const int cnt4 = n*GD/4;                       // 1.6M
  const int ncastb = (cnt4 + 255)/256;           // 6250
  const int histb  = (E + 255)/256;              // 2344

  hipMemsetAsync(cnt_rd, 0, (size_t)8*n*4, stream);

  k_prep<<<576 + 256 + ncastb + histb, 256, 0, stream>>>(
      comp, basis, root, B1t, wk, wq, wv, wsk, bk, bq, bv, bs, B2t, Bb,
      (const float4*)x, (uint2*)xbf, cnt4, edst, etype, cnt_rd, E, n);
  k_scanA<<<nblk_rd, 1024, 0, stream>>>(cnt_rd, off_rd, btot_rd, 8*n);
  k_scanB<<<nblk_rd, 1024, 0, stream>>>(btot_rd, off_rd, cur_rd, 8*n, E);
  k_scatter_rd<<<(E + 255)/256, 256, 0, stream>>>(esrc, edst, etype, cur_rd, pk_rd, E, n);
  k_fused1<<<npad/32, 512, 0, stream>>>(off_rd, pk_rd, xbf, B1t, bias1, hbuf, n);
  k_gemm2<<<dim3(npad/128, 4), 256, 0, stream>>>(hbuf, B2t, Bb, kqv, skipb, n);
  k_edge2<<<(n + 3)/4, 256, 0, stream>>>(off_rd, pk_rd, kqv, skipb, out, n);
}

// Round 11
// 379.195 us; speedup vs baseline: 1.0632x; 1.0632x over previous
//
#include <hip/hip_runtime.h>
#include <stdint.h>

#define GD 128
#define H1 128
#define H2 128
#define NBASES 32
#define NREL 8
#define KZ 1152   // Z width = 8*128 + 128

typedef __attribute__((ext_vector_type(8))) short bf16x8;
typedef __attribute__((ext_vector_type(4))) float f32x4;

static inline size_t align256(size_t x){ return (x + 255) & ~(size_t)255; }

__device__ __forceinline__ float bf2f(uint32_t u16){
  union { uint32_t u; float f; } c; c.u = (u16 & 0xffffu) << 16; return c.f;
}
__device__ __forceinline__ unsigned short f2bf(float f){
  union { float f; uint32_t u; } c; c.f = f;
  uint32_t u = c.u;
  u += 0x7fffu + ((u >> 16) & 1u);   // RTNE (finite inputs)
  return (unsigned short)(u >> 16);
}
__device__ __forceinline__ uint32_t pkbf(float a, float b){
  union { float f; uint32_t u; } ca, cb; ca.f = a; cb.f = b;
  return __builtin_amdgcn_perm(cb.u + 0x8000u, ca.u + 0x8000u, 0x07060302u);
}

__device__ __forceinline__ void async_copy16(void* lds_dst, const void* gsrc){
  __builtin_amdgcn_global_load_lds(
      (const __attribute__((address_space(1))) uint32_t*)gsrc,
      (__attribute__((address_space(3))) uint32_t*)lds_dst, 16, 0, 0);
}

// ==== merged prep: Bz build | B2t build | x cast | xbf pad zero | r-major hist ====
__global__ void k_prep(const float* __restrict__ comp, const float* __restrict__ basis,
                       const float* __restrict__ root, unsigned short* __restrict__ Bz,
                       const float* __restrict__ wk, const float* __restrict__ wq,
                       const float* __restrict__ wv, const float* __restrict__ wsk,
                       const float* __restrict__ bk, const float* __restrict__ bq,
                       const float* __restrict__ bv, const float* __restrict__ bs,
                       unsigned short* __restrict__ B2t, float* __restrict__ Bb,
                       const float4* __restrict__ x, uint2* __restrict__ xout, int cnt4,
                       uint32_t* __restrict__ xpadz, int npadz,
                       const int* __restrict__ edst, const int* __restrict__ etyp,
                       int* __restrict__ cnt, int E, int n){
  int b = blockIdx.x, t = threadIdx.x;
  if (b < 576){
    // Bz[row=r*128+o][i]: W_r[i,o] (r<8) or root[i,o] (rows 1024..1151)
    int idx = b*256 + t;                 // < 147456 = 1152*128
    int row = idx >> 7, i = idx & 127;
    int r = row >> 7, o = row & 127;
    float v;
    if (r < 8){
      float acc = 0.f;
      #pragma unroll
      for (int bb = 0; bb < NBASES; ++bb)
        acc += comp[r*NBASES + bb] * basis[((size_t)bb*GD + i)*H1 + o];
      v = acc;
    } else {
      v = root[(size_t)i*H1 + o];
    }
    Bz[idx] = f2bf(v);
  } else if (b < 576 + 256){
    int idx = (b - 576)*256 + t;         // < 65536 = 512*H1
    int c = idx / H1, k = idx % H1;
    const float* w = (c < 128) ? wk : (c < 256) ? wq : (c < 384) ? wv : wsk;
    B2t[idx] = f2bf(w[(size_t)k*H2 + (c & 127)]);
    if (idx < 512){
      const float* bia = (idx < 128) ? bk : (idx < 256) ? bq : (idx < 384) ? bv : bs;
      Bb[idx] = bia[idx & 127];
    }
  } else {
    int cb = b - (576 + 256);
    int ncastb = (cnt4 + 255) >> 8;
    if (cb < ncastb){
      int i = cb*256 + t;
      if (i < cnt4){
        float4 v = x[i];
        uint2 o; o.x = pkbf(v.x, v.y); o.y = pkbf(v.z, v.w);
        xout[i] = o;
      }
    } else if (cb < ncastb + 12){
      int i = (cb - ncastb)*256 + t;
      if (i < npadz) xpadz[i] = 0u;      // zero xbf pad rows
    } else {
      int e = (cb - ncastb - 12)*256 + t;
      if (e < E) atomicAdd(&cnt[etyp[e]*n + edst[e]], 1);
    }
  }
}

// ---- parallel scan, stage A ----
__global__ void k_scanA(const int* __restrict__ deg, int* __restrict__ off,
                        int* __restrict__ btot, int len){
  __shared__ int wsum[16];
  int t = threadIdx.x, lane = t & 63, w = t >> 6;
  int i0 = blockIdx.x*8192 + t*8;
  int v[8];
  if (i0 + 7 < len){
    int4 va = *(const int4*)(deg + i0);
    int4 vb = *(const int4*)(deg + i0 + 4);
    v[0]=va.x; v[1]=va.y; v[2]=va.z; v[3]=va.w;
    v[4]=vb.x; v[5]=vb.y; v[6]=vb.z; v[7]=vb.w;
  } else {
    #pragma unroll
    for (int u = 0; u < 8; ++u) v[u] = (i0+u < len) ? deg[i0+u] : 0;
  }
  int s[8]; s[0] = v[0];
  #pragma unroll
  for (int u = 1; u < 8; ++u) s[u] = s[u-1] + v[u];
  int x = s[7];
  #pragma unroll
  for (int d = 1; d < 64; d <<= 1){
    int u = __shfl_up(x, d, 64);
    if (lane >= d) x += u;
  }
  if (lane == 63) wsum[w] = x;
  __syncthreads();
  if (t < 16){
    int y = wsum[t];
    #pragma unroll
    for (int d = 1; d < 16; d <<= 1){
      int u = __shfl_up(y, d, 16);
      if (t >= d) y += u;
    }
    wsum[t] = y;
  }
  __syncthreads();
  int woff = (w > 0) ? wsum[w-1] : 0;
  int excl = woff + x - s[7];
  #pragma unroll
  for (int u = 0; u < 8; ++u)
    if (i0+u < len) off[i0+u] = excl + s[u] - v[u];
  if (t == 0) btot[blockIdx.x] = wsum[15];
}

// ---- scan stage B ----
__global__ void k_scanB(const int* __restrict__ btot, int* __restrict__ off,
                        int* __restrict__ cursor, int len, int sentinel){
  int t = threadIdx.x, bid = blockIdx.x;
  int add = 0;
  for (int j = 0; j < bid; ++j) add += btot[j];
  int i0 = bid*8192 + t*8;
  #pragma unroll
  for (int u = 0; u < 8; ++u){
    int i = i0 + u;
    if (i < len){ int val = off[i] + add; off[i] = val; cursor[i] = val; }
  }
  if (bid == 0 && t == 0) off[len] = sentinel;
}

// pk[pos] = src, (r,dst)-sorted
__global__ void k_scatter_rd(const int* __restrict__ src, const int* __restrict__ dst,
                             const int* __restrict__ typ, int* __restrict__ cursor,
                             int* __restrict__ pk, int E, int n){
  int e = blockIdx.x*blockDim.x + threadIdx.x;
  if (e >= E) return;
  int pos = atomicAdd(&cursor[typ[e]*n + dst[e]], 1);
  pk[pos] = src[e];
}

// ---- zgemm (m97-style): Z(bf16)[npad,1152] = xbf[npad,128] @ Bz^T ----
__launch_bounds__(256)
__global__ void k_zgemm(const unsigned short* __restrict__ A, const unsigned short* __restrict__ Bt,
                        unsigned short* __restrict__ Z){
  __shared__ char lds[16384];
  int t = threadIdx.x, lane = t & 63, wave = t >> 6;
  int row0 = blockIdx.x * 128;
  int c0 = blockIdx.y * 128;
  int mrow = lane & 15, quad = lane >> 4;
  int wrow = (wave & 1) * 64, wcol = (wave >> 1) * 64;
  int s = (mrow >> 1) & 3;

  const unsigned short* Asrc = A + (size_t)(row0 + (t >> 2))*H1 + (((t & 3) ^ ((t >> 3) & 3)) << 3);
  const unsigned short* Bsrc = Bt + (size_t)(c0 + (t >> 2))*H1 + (((t & 3) ^ ((t >> 3) & 3)) << 3);
  char* ldsw = lds + wave*1024;

  int aoff = (wrow + mrow)*64 + ((quad ^ s) << 4);
  int boff = 8192 + (wcol + mrow)*64 + ((quad ^ s) << 4);

  f32x4 acc[4][4];
  #pragma unroll
  for (int i = 0; i < 4; ++i)
    #pragma unroll
    for (int j = 0; j < 4; ++j) acc[i][j] = (f32x4){0.f,0.f,0.f,0.f};

  #pragma unroll
  for (int kt = 0; kt < H1; kt += 32){
    __syncthreads();
    async_copy16(ldsw,         Asrc + kt);
    async_copy16(ldsw + 4096,  Asrc + (size_t)64*H1 + kt);
    async_copy16(ldsw + 8192,  Bsrc + kt);
    async_copy16(ldsw + 12288, Bsrc + (size_t)64*H1 + kt);
    __syncthreads();
    bf16x8 af[4], bf[4];
    #pragma unroll
    for (int i = 0; i < 4; ++i) af[i] = *(const bf16x8*)(lds + aoff + i*1024);
    #pragma unroll
    for (int j = 0; j < 4; ++j) bf[j] = *(const bf16x8*)(lds + boff + j*1024);
    #pragma unroll
    for (int i = 0; i < 4; ++i)
      #pragma unroll
      for (int j = 0; j < 4; ++j)
        acc[i][j] = __builtin_amdgcn_mfma_f32_16x16x32_bf16(af[i], bf[j], acc[i][j], 0, 0, 0);
  }
  #pragma unroll
  for (int j = 0; j < 4; ++j){
    int col = c0 + wcol + j*16 + mrow;
    #pragma unroll
    for (int i = 0; i < 4; ++i)
      #pragma unroll
      for (int rg = 0; rg < 4; ++rg){
        int row = row0 + wrow + i*16 + quad*4 + rg;
        Z[(size_t)row*KZ + col] = f2bf(acc[i][j][rg]);
      }
  }
}

// ---- one wave per dst node: h[d] = sum_e Z[src, r-block]*(1/cnt) + Z[d,root] + bias1 ----
__global__ void k_edge1(const int* __restrict__ off_rd, const int* __restrict__ pk_rd,
                        const unsigned short* __restrict__ Zb,
                        const float* __restrict__ bias1,
                        unsigned short* __restrict__ h, int n, int npad){
  int wid = blockIdx.x*(blockDim.x >> 6) + (threadIdx.x >> 6);
  int lane = threadIdx.x & 63;
  if (wid >= npad) return;
  uint32_t* hrow = (uint32_t*)(h + (size_t)wid*H1);
  if (wid >= n){ hrow[lane] = 0u; return; }
  const uint32_t* Z32 = (const uint32_t*)Zb;
  int r8 = lane & 7;
  int o_r = off_rd[(size_t)r8*n + wid];
  int e_r = off_rd[(size_t)r8*n + wid + 1];
  int c_r = e_r - o_r;
  float ic_r = (c_r > 0) ? (1.f/(float)c_r) : 0.f;
  int c0_ = __builtin_amdgcn_readlane(c_r, 0), c1_ = __builtin_amdgcn_readlane(c_r, 1);
  int c2_ = __builtin_amdgcn_readlane(c_r, 2), c3_ = __builtin_amdgcn_readlane(c_r, 3);
  int c4_ = __builtin_amdgcn_readlane(c_r, 4), c5_ = __builtin_amdgcn_readlane(c_r, 5);
  int c6_ = __builtin_amdgcn_readlane(c_r, 6), c7_ = __builtin_amdgcn_readlane(c_r, 7);
  int o0_ = __builtin_amdgcn_readlane(o_r, 0), o1_ = __builtin_amdgcn_readlane(o_r, 1);
  int o2_ = __builtin_amdgcn_readlane(o_r, 2), o3_ = __builtin_amdgcn_readlane(o_r, 3);
  int o4_ = __builtin_amdgcn_readlane(o_r, 4), o5_ = __builtin_amdgcn_readlane(o_r, 5);
  int o6_ = __builtin_amdgcn_readlane(o_r, 6), o7_ = __builtin_amdgcn_readlane(o_r, 7);
  float i0f = __int_as_float(__builtin_amdgcn_readlane(__float_as_int(ic_r), 0));
  float i1f = __int_as_float(__builtin_amdgcn_readlane(__float_as_int(ic_r), 1));
  float i2f = __int_as_float(__builtin_amdgcn_readlane(__float_as_int(ic_r), 2));
  float i3f = __int_as_float(__builtin_amdgcn_readlane(__float_as_int(ic_r), 3));
  float i4f = __int_as_float(__builtin_amdgcn_readlane(__float_as_int(ic_r), 4));
  float i5f = __int_as_float(__builtin_amdgcn_readlane(__float_as_int(ic_r), 5));
  float i6f = __int_as_float(__builtin_amdgcn_readlane(__float_as_int(ic_r), 6));
  float i7f = __int_as_float(__builtin_amdgcn_readlane(__float_as_int(ic_r), 7));
  int p1 = c0_, p2 = p1 + c1_, p3 = p2 + c2_, p4 = p3 + c3_;
  int p5 = p4 + c4_, p6 = p5 + c5_, p7 = p6 + c6_, dg = p7 + c7_;

  float a0 = 0.f, a1 = 0.f;
  for (int jb = 0; jb < dg; jb += 64){
    int i = jb + lane;
    int adj = o0_, rel = 0;
    float wv = i0f;
    adj = (i >= p1) ? (o1_ - p1) : adj;  rel += (i >= p1);  wv = (i >= p1) ? i1f : wv;
    adj = (i >= p2) ? (o2_ - p2) : adj;  rel += (i >= p2);  wv = (i >= p2) ? i2f : wv;
    adj = (i >= p3) ? (o3_ - p3) : adj;  rel += (i >= p3);  wv = (i >= p3) ? i3f : wv;
    adj = (i >= p4) ? (o4_ - p4) : adj;  rel += (i >= p4);  wv = (i >= p4) ? i4f : wv;
    adj = (i >= p5) ? (o5_ - p5) : adj;  rel += (i >= p5);  wv = (i >= p5) ? i5f : wv;
    adj = (i >= p6) ? (o6_ - p6) : adj;  rel += (i >= p6);  wv = (i >= p6) ? i6f : wv;
    adj = (i >= p7) ? (o7_ - p7) : adj;  rel += (i >= p7);  wv = (i >= p7) ? i7f : wv;
    int m = dg - jb; if (m > 64) m = 64;
    int pj = (lane < m) ? pk_rd[adj + i] : 0;
    int gidx = pj*(KZ/2) + rel*64;       // uint32 index of this edge's Z r-block
    int jj = 0;
    for (; jj + 8 <= m; jj += 8){
      uint32_t g[8]; float wgt[8];
      #pragma unroll
      for (int k = 0; k < 8; ++k){
        int gx = __builtin_amdgcn_readlane(gidx, jj + k);
        wgt[k] = __int_as_float(__builtin_amdgcn_readlane(__float_as_int(wv), jj + k));
        g[k] = Z32[(size_t)(uint32_t)gx + lane];
      }
      #pragma unroll
      for (int k = 0; k < 8; ++k){
        a0 += bf2f(g[k]) * wgt[k];
        a1 += bf2f(g[k] >> 16) * wgt[k];
      }
    }
    for (; jj + 4 <= m; jj += 4){
      uint32_t g[4]; float wgt[4];
      #pragma unroll
      for (int k = 0; k < 4; ++k){
        int gx = __builtin_amdgcn_readlane(gidx, jj + k);
        wgt[k] = __int_as_float(__builtin_amdgcn_readlane(__float_as_int(wv), jj + k));
        g[k] = Z32[(size_t)(uint32_t)gx + lane];
      }
      #pragma unroll
      for (int k = 0; k < 4; ++k){
        a0 += bf2f(g[k]) * wgt[k];
        a1 += bf2f(g[k] >> 16) * wgt[k];
      }
    }
    for (; jj < m; ++jj){
      int gx = __builtin_amdgcn_readlane(gidx, jj);
      float wg = __int_as_float(__builtin_amdgcn_readlane(__float_as_int(wv), jj));
      uint32_t gg = Z32[(size_t)(uint32_t)gx + lane];
      a0 += bf2f(gg) * wg;
      a1 += bf2f(gg >> 16) * wg;
    }
  }
  uint32_t zr = Z32[(size_t)wid*(KZ/2) + 512 + lane];
  float2 bb = ((const float2*)bias1)[lane];
  hrow[lane] = pkbf(a0 + bf2f(zr) + bb.x, a1 + bf2f(zr >> 16) + bb.y);
}

// ---- GEMM2 (m97-style): [npad,512] = h @ B2t^T + Bb; skip -> skipb(bf16) ----
__launch_bounds__(256)
__global__ void k_gemm2(const unsigned short* __restrict__ A, const unsigned short* __restrict__ Bt,
                        const float* __restrict__ Bb, unsigned short* __restrict__ kqv,
                        unsigned short* __restrict__ skipb, int n){
  __shared__ char lds[16384];
  int t = threadIdx.x, lane = t & 63, wave = t >> 6;
  int row0 = blockIdx.x * 128;
  int c0 = blockIdx.y * 128;
  int mrow = lane & 15, quad = lane >> 4;
  int wrow = (wave & 1) * 64, wcol = (wave >> 1) * 64;
  int s = (mrow >> 1) & 3;

  const unsigned short* Asrc = A + (size_t)(row0 + (t >> 2))*H1 + (((t & 3) ^ ((t >> 3) & 3)) << 3);
  const unsigned short* Bsrc = Bt + (size_t)(c0 + (t >> 2))*H1 + (((t & 3) ^ ((t >> 3) & 3)) << 3);
  char* ldsw = lds + wave*1024;

  int aoff = (wrow + mrow)*64 + ((quad ^ s) << 4);
  int boff = 8192 + (wcol + mrow)*64 + ((quad ^ s) << 4);

  f32x4 acc[4][4];
  #pragma unroll
  for (int i = 0; i < 4; ++i)
    #pragma unroll
    for (int j = 0; j < 4; ++j) acc[i][j] = (f32x4){0.f,0.f,0.f,0.f};

  #pragma unroll
  for (int kt = 0; kt < H1; kt += 32){
    __syncthreads();
    async_copy16(ldsw,         Asrc + kt);
    async_copy16(ldsw + 4096,  Asrc + (size_t)64*H1 + kt);
    async_copy16(ldsw + 8192,  Bsrc + kt);
    async_copy16(ldsw + 12288, Bsrc + (size_t)64*H1 + kt);
    __syncthreads();
    bf16x8 af[4], bf[4];
    #pragma unroll
    for (int i = 0; i < 4; ++i) af[i] = *(const bf16x8*)(lds + aoff + i*1024);
    #pragma unroll
    for (int j = 0; j < 4; ++j) bf[j] = *(const bf16x8*)(lds + boff + j*1024);
    #pragma unroll
    for (int i = 0; i < 4; ++i)
      #pragma unroll
      for (int j = 0; j < 4; ++j)
        acc[i][j] = __builtin_amdgcn_mfma_f32_16x16x32_bf16(af[i], bf[j], acc[i][j], 0, 0, 0);
  }
  #pragma unroll
  for (int j = 0; j < 4; ++j){
    int col = c0 + wcol + j*16 + mrow;
    float bcol = Bb[col];
    #pragma unroll
    for (int i = 0; i < 4; ++i)
      #pragma unroll
      for (int rg = 0; rg < 4; ++rg){
        int rr = row0 + wrow + i*16 + quad*4 + rg;
        if (rr >= n) continue;
        float v = acc[i][j][rg] + bcol;
        if (col < 128){
          kqv[(size_t)rr*384 + col] = f2bf(v);
        } else if (col < 256){
          int jj = col - 128;
          kqv[(size_t)rr*384 + 128 + ((jj >> 1) << 2) + (jj & 1)] = f2bf(v);
        } else if (col < 384){
          int jj = col - 256;
          kqv[(size_t)rr*384 + 128 + ((jj >> 1) << 2) + 2 + (jj & 1)] = f2bf(v);
        } else {
          skipb[(size_t)rr*H2 + (col - 384)] = f2bf(v);
        }
      }
  }
}

// ---- one wave per dst node: out = sum_e sigmoid(k+q)*v + skip (pure write) ----
__global__ void k_edge2(const int* __restrict__ off_rd, const int* __restrict__ pk_rd,
                        const unsigned short* __restrict__ kqv,
                        const unsigned short* __restrict__ skipb,
                        float* __restrict__ out, int n){
  int wid = blockIdx.x*(blockDim.x >> 6) + (threadIdx.x >> 6);
  int lane = threadIdx.x & 63;
  if (wid >= n) return;
  const uint32_t* kv32 = (const uint32_t*)kqv;
  int r = lane & 7;
  int o_r = off_rd[(size_t)r*n + wid];
  int e_r = off_rd[(size_t)r*n + wid + 1];
  int c_r = e_r - o_r;
  int c0_ = __builtin_amdgcn_readlane(c_r, 0), c1_ = __builtin_amdgcn_readlane(c_r, 1);
  int c2_ = __builtin_amdgcn_readlane(c_r, 2), c3_ = __builtin_amdgcn_readlane(c_r, 3);
  int c4_ = __builtin_amdgcn_readlane(c_r, 4), c5_ = __builtin_amdgcn_readlane(c_r, 5);
  int c6_ = __builtin_amdgcn_readlane(c_r, 6), c7_ = __builtin_amdgcn_readlane(c_r, 7);
  int o0_ = __builtin_amdgcn_readlane(o_r, 0), o1_ = __builtin_amdgcn_readlane(o_r, 1);
  int o2_ = __builtin_amdgcn_readlane(o_r, 2), o3_ = __builtin_amdgcn_readlane(o_r, 3);
  int o4_ = __builtin_amdgcn_readlane(o_r, 4), o5_ = __builtin_amdgcn_readlane(o_r, 5);
  int o6_ = __builtin_amdgcn_readlane(o_r, 6), o7_ = __builtin_amdgcn_readlane(o_r, 7);
  int p1 = c0_, p2 = p1 + c1_, p3 = p2 + c2_, p4 = p3 + c3_;
  int p5 = p4 + c4_, p6 = p5 + c5_, p7 = p6 + c6_, dg = p7 + c7_;

  uint32_t ku = kv32[(size_t)wid*192 + lane];
  float k0 = bf2f(ku), k1 = bf2f(ku >> 16);
  float a0 = 0.f, a1 = 0.f;
  for (int jb = 0; jb < dg; jb += 64){
    int i = jb + lane;
    int adj = o0_;
    adj = (i >= p1) ? (o1_ - p1) : adj;
    adj = (i >= p2) ? (o2_ - p2) : adj;
    adj = (i >= p3) ? (o3_ - p3) : adj;
    adj = (i >= p4) ? (o4_ - p4) : adj;
    adj = (i >= p5) ? (o5_ - p5) : adj;
    adj = (i >= p6) ? (o6_ - p6) : adj;
    adj = (i >= p7) ? (o7_ - p7) : adj;
    int m = dg - jb; if (m > 64) m = 64;
    int pj = (lane < m) ? pk_rd[adj + i] : 0;
    int jj = 0;
    for (; jj + 8 <= m; jj += 8){
      uint2 q[8];
      #pragma unroll
      for (int k = 0; k < 8; ++k){
        int s = __builtin_amdgcn_readlane(pj, jj + k);
        q[k] = *(const uint2*)(kv32 + (size_t)s*192 + 64 + lane*2);
      }
      #pragma unroll
      for (int k = 0; k < 8; ++k){
        float qq0 = bf2f(q[k].x), qq1 = bf2f(q[k].x >> 16);
        float vv0 = bf2f(q[k].y), vv1 = bf2f(q[k].y >> 16);
        float g0 = 1.f / (1.f + __expf(-(k0 + qq0)));
        float g1 = 1.f / (1.f + __expf(-(k1 + qq1)));
        a0 += g0*vv0; a1 += g1*vv1;
      }
    }
    for (; jj + 4 <= m; jj += 4){
      uint2 q[4];
      #pragma unroll
      for (int k = 0; k < 4; ++k){
        int s = __builtin_amdgcn_readlane(pj, jj + k);
        q[k] = *(const uint2*)(kv32 + (size_t)s*192 + 64 + lane*2);
      }
      #pragma unroll
      for (int k = 0; k < 4; ++k){
        float qq0 = bf2f(q[k].x), qq1 = bf2f(q[k].x >> 16);
        float vv0 = bf2f(q[k].y), vv1 = bf2f(q[k].y >> 16);
        float g0 = 1.f / (1.f + __expf(-(k0 + qq0)));
        float g1 = 1.f / (1.f + __expf(-(k1 + qq1)));
        a0 += g0*vv0; a1 += g1*vv1;
      }
    }
    for (; jj < m; ++jj){
      int s = __builtin_amdgcn_readlane(pj, jj);
      uint2 qc = *(const uint2*)(kv32 + (size_t)s*192 + 64 + lane*2);
      float qq0 = bf2f(qc.x), qq1 = bf2f(qc.x >> 16);
      float vv0 = bf2f(qc.y), vv1 = bf2f(qc.y >> 16);
      float g0 = 1.f / (1.f + __expf(-(k0 + qq0)));
      float g1 = 1.f / (1.f + __expf(-(k1 + qq1)));
      a0 += g0*vv0; a1 += g1*vv1;
    }
  }
  uint32_t sk = ((const uint32_t*)skipb)[(size_t)wid*64 + lane];
  float2 cur; cur.x = a0 + bf2f(sk); cur.y = a1 + bf2f(sk >> 16);
  ((float2*)(out + (size_t)wid*H2))[lane] = cur;
}

extern "C" void kernel_launch(void* const* d_in, const int* in_sizes, int n_in,
                              void* d_out, int out_size, void* d_ws, size_t ws_size,
                              hipStream_t stream){
  const float* x     = (const float*)d_in[0];
  const int*   eidx  = (const int*)  d_in[1];
  const int*   etype = (const int*)  d_in[3];
  const float* basis = (const float*)d_in[4];
  const float* comp  = (const float*)d_in[5];
  const float* root  = (const float*)d_in[6];
  const float* bias1 = (const float*)d_in[7];
  const float* wk    = (const float*)d_in[8];
  const float* bk    = (const float*)d_in[9];
  const float* wq    = (const float*)d_in[10];
  const float* bq    = (const float*)d_in[11];
  const float* wv    = (const float*)d_in[12];
  const float* bv    = (const float*)d_in[13];
  const float* wsk   = (const float*)d_in[14];
  const float* bs    = (const float*)d_in[15];
  const int n = in_sizes[0] / GD;          // 50000
  const int E = in_sizes[3];               // 600000
  const int npad = (n + 127) & ~127;       // 50048
  const int* esrc = eidx;
  const int* edst = eidx + E;
  float* out = (float*)d_out;

  char* w = (char*)d_ws;
  size_t off = 0;
  unsigned short* xbf  = (unsigned short*)(w + off); off = align256(off + (size_t)npad*GD*2);
  unsigned short* Zbuf = (unsigned short*)(w + off); off = align256(off + (size_t)npad*KZ*2);
  unsigned short* Bz   = (unsigned short*)(w + off); off = align256(off + (size_t)KZ*H1*2);
  unsigned short* B2t  = (unsigned short*)(w + off); off = align256(off + (size_t)512*H1*2);
  float* Bb            = (float*)(w + off);          off = align256(off + 512*4);
  unsigned short* hbuf = (unsigned short*)(w + off); off = align256(off + (size_t)npad*H1*2);
  unsigned short* kqv  = (unsigned short*)(w + off); off = align256(off + (size_t)n*384*2);
  unsigned short* skipb= (unsigned short*)(w + off); off = align256(off + (size_t)npad*H2*2);
  int* cnt_rd          = (int*)(w + off);            off = align256(off + (size_t)(8*n+4)*4);
  int* off_rd          = (int*)(w + off);            off = align256(off + (size_t)(8*n+1)*4);
  int* cur_rd          = (int*)(w + off);            off = align256(off + (size_t)8*n*4);
  int* btot_rd         = (int*)(w + off);            off = align256(off + 64*4);
  int* pk_rd           = (int*)(w + off);            off = align256(off + (size_t)E*4);

  const int nblk_rd = (8*n + 8191) / 8192;       // 49
  const int cnt4 = n*GD/4;                       // 1.6M
  const int ncastb = (cnt4 + 255)/256;           // 6250
  const int histb  = (E + 255)/256;              // 2344
  const int npadz  = (npad - n)*GD/2;            // pad uint32 count

  hipMemsetAsync(cnt_rd, 0, (size_t)8*n*4, stream);

  k_prep<<<576 + 256 + ncastb + 12 + histb, 256, 0, stream>>>(
      comp, basis, root, Bz, wk, wq, wv, wsk, bk, bq, bv, bs, B2t, Bb,
      (const float4*)x, (uint2*)xbf, cnt4,
      (uint32_t*)(xbf + (size_t)n*GD), npadz,
      edst, etype, cnt_rd, E, n);
  k_scanA<<<nblk_rd, 1024, 0, stream>>>(cnt_rd, off_rd, btot_rd, 8*n);
  k_scanB<<<nblk_rd, 1024, 0, stream>>>(btot_rd, off_rd, cur_rd, 8*n, E);
  k_scatter_rd<<<(E + 255)/256, 256, 0, stream>>>(esrc, edst, etype, cur_rd, pk_rd, E, n);
  k_zgemm<<<dim3(npad/128, KZ/128), 256, 0, stream>>>(xbf, Bz, Zbuf);
  k_edge1<<<(npad + 3)/4, 256, 0, stream>>>(off_rd, pk_rd, Zbuf, bias1, hbuf, n, npad);
  k_gemm2<<<dim3(npad/128, 4), 256, 0, stream>>>(hbuf, B2t, Bb, kqv, skipb, n);
  k_edge2<<<(n + 3)/4, 256, 0, stream>>>(off_rd, pk_rd, kqv, skipb, out, n);
}